// Round 7
// baseline (473.961 us; speedup 1.0000x reference)
//
#include <hip/hip_runtime.h>
#include <hip/hip_bf16.h>

// CrossAttn: softmax over QUERY dim n =>
//   out[n,d] = sum_m exp(s[n,m]) * v[m,d] / Z[m],  Z[m] = sum_n exp(s[n,m]).
// Pipeline (bf16 MFMA, fp32 accum):
//   cvt fp32->bf16; q = y Wq^T + bq; kv = x Wkv^T + bkv (k|v fused);
//   P = exp(q k^T * scale) with Z[m] colsum; vt[d,m] = v[m,d]/Z[m];
//   out = P vt^T (fp32).
//
// GEMM: 128x128 tile, BK=32, 256 thr / 4 waves (2x2) -- the structure that
// measured 642 TF here in R1 -- plus:
//  * double-buffered LDS (32 KiB total -> 4-5 blocks/CU of TLP, vs R4's
//    1-block 96KiB deep pipeline that starved the CU at every barrier)
//  * early STAGE: issue tile t+1's global_load_lds BEFORE compute(t); one
//    __syncthreads() per tile (vmcnt0+lgkm0+barrier) -- removes R1's
//    exposed stage wait (stage->immediate drain).
//  * R4-verified LDS swizzle (conflicts 4.7M -> 0): linear gload_lds dest,
//    pre-swizzled global source js = tid ^ ((tid>>3)&7); read byte addr
//    (row*64 + kg*16) ^ (((fl>>1)&7)<<4).  Same 64B-row geometry as R4.
// Race ledger (dbuf, stage-1-ahead):
//   WAR: STAGE(t+1) writes buf[(t+1)&1], last read in iter t-1 whose reads
//        retired before iter t-1's __syncthreads -> safe.
//   RAW: reads of buf[t&1] need tile t landed: iter t-1's __syncthreads
//        drained vmcnt(0) (tile t staged during iter t-1) -> safe.

using bf16 = __bf16;
typedef __attribute__((ext_vector_type(8))) __bf16 bf16x8;
typedef __attribute__((ext_vector_type(4))) float f32x4;

#define GLB_AS __attribute__((address_space(1)))
#define LDS_AS __attribute__((address_space(3)))

__device__ __forceinline__ void gload_lds16(const void* g, void* l) {
  __builtin_amdgcn_global_load_lds((const GLB_AS uint32_t*)g,
                                   (LDS_AS uint32_t*)l, 16, 0, 0);
}

enum { EPI_BIAS = 0, EPI_EXP = 1, EPI_OUT = 2 };

// C[M,N] = A[M,K] * Bt[N,K]^T.  M%128==0, N%128==0, K%32==0, K/32 >= 2.
template <int EPI>
__global__ __launch_bounds__(256, 4) void gemm128(
    const bf16* __restrict__ A, const bf16* __restrict__ Bt,
    void* __restrict__ Cv, const float* __restrict__ bias,
    float* __restrict__ Z, int M, int N, int K, int ldA, int ldB, int ldC,
    long sA, long sB, long sC, float scale) {
  __shared__ __align__(16) bf16 As[2 * 4096];  // 2 bufs x 128x32 (8KB each)
  __shared__ __align__(16) bf16 Bs[2 * 4096];

  const int bz = blockIdx.z;
  const bf16* Ab = A + (long)bz * sA;
  const bf16* Bb = Bt + (long)bz * sB;

  const int tid = threadIdx.x;
  const int lane = tid & 63;
  const int wave = tid >> 6;
  const int wm = (wave >> 1) * 64;
  const int wn = (wave & 1) * 64;
  const int fl = lane & 15;
  const int kg = lane >> 4;
  const long m0 = (long)blockIdx.x * 128;
  const long n0 = (long)blockIdx.y * 128;

  f32x4 acc[4][4] = {};

  // staging: 512 chunks of 16B per tile; thread t handles chunks {t, t+256}.
  // LDS dest linear (chunk c -> byte c*16); global source pre-swizzled.
  const int js = tid ^ ((tid >> 3) & 7);
  const int srow = js >> 2;        // 0..63
  const int scol = (js & 3) * 8;
  const bf16* gAc = Ab + (m0 + srow) * (long)ldA + scol;
  const bf16* gBc = Bb + (n0 + srow) * (long)ldB + scol;
  char* Abase = (char*)As;
  char* Bbase = (char*)Bs;

#define STAGE(tt)                                            \
  {                                                          \
    char* _da = Abase + ((tt)&1) * 8192 + tid * 16;          \
    char* _db = Bbase + ((tt)&1) * 8192 + tid * 16;          \
    const bf16* _ga = gAc + (long)(tt) * 32;                 \
    const bf16* _gb = gBc + (long)(tt) * 32;                 \
    gload_lds16(_ga, _da);                                   \
    gload_lds16(_ga + 64 * (long)ldA, _da + 4096);           \
    gload_lds16(_gb, _db);                                   \
    gload_lds16(_gb + 64 * (long)ldB, _db + 4096);           \
  }

  // swizzled read bases (R4-verified conflict-free; bits 4-6 XOR)
  const int swz = ((fl >> 1) & 7) << 4;
  const int abase = ((wm + fl) * 64 + kg * 16) ^ swz;  // + i*1024 per frag
  const int bbase = ((wn + fl) * 64 + kg * 16) ^ swz;

  const int nt = K >> 5;

  STAGE(0)
  __syncthreads();  // vmcnt(0): tile 0 landed

  for (int t = 0; t < nt; ++t) {
    if (t + 1 < nt) STAGE(t + 1);  // in flight across this tile's compute
    const char* Asl = Abase + (t & 1) * 8192;
    const char* Bsl = Bbase + (t & 1) * 8192;
    bf16x8 a[4], b[4];
#pragma unroll
    for (int i = 0; i < 4; i++) a[i] = *(const bf16x8*)(Asl + abase + i * 1024);
#pragma unroll
    for (int i = 0; i < 4; i++) b[i] = *(const bf16x8*)(Bsl + bbase + i * 1024);
#pragma unroll
    for (int i = 0; i < 4; i++)
#pragma unroll
      for (int j = 0; j < 4; j++)
        acc[i][j] = __builtin_amdgcn_mfma_f32_16x16x32_bf16(a[i], b[j],
                                                            acc[i][j], 0, 0, 0);
    __syncthreads();  // drains vmcnt(0) (t+1 landed) + all waves done reading
  }
#undef STAGE

  // C/D frag mapping (verified R1/R3/R4): col = lane&15, row = kg*4 + e
  if constexpr (EPI == EPI_BIAS) {
    bf16* Cb = (bf16*)Cv + (long)bz * sC;
#pragma unroll
    for (int j = 0; j < 4; j++) {
      const long cc = n0 + wn + j * 16 + fl;
      const float bc = bias[cc];
#pragma unroll
      for (int i = 0; i < 4; i++)
#pragma unroll
        for (int e = 0; e < 4; e++) {
          const long rr = m0 + wm + i * 16 + kg * 4 + e;
          Cb[rr * ldC + cc] = (bf16)(acc[i][j][e] + bc);
        }
    }
  } else if constexpr (EPI == EPI_EXP) {
    bf16* Cb = (bf16*)Cv + (long)bz * sC;
    float* Zb = Z + (long)bz * N;
#pragma unroll
    for (int j = 0; j < 4; j++) {
      const long cc = n0 + wn + j * 16 + fl;
      float zp = 0.f;
#pragma unroll
      for (int i = 0; i < 4; i++)
#pragma unroll
        for (int e = 0; e < 4; e++) {
          const long rr = m0 + wm + i * 16 + kg * 4 + e;
          const float ex = __expf(acc[i][j][e] * scale);
          zp += ex;
          Cb[rr * ldC + cc] = (bf16)ex;
        }
      atomicAdd(&Zb[cc], zp);  // column sum over query rows n
    }
  } else {
    float* Cb = (float*)Cv + (long)bz * sC;
#pragma unroll
    for (int j = 0; j < 4; j++) {
      const long cc = n0 + wn + j * 16 + fl;
#pragma unroll
      for (int i = 0; i < 4; i++)
#pragma unroll
        for (int e = 0; e < 4; e++) {
          const long rr = m0 + wm + i * 16 + kg * 4 + e;
          Cb[rr * ldC + cc] = acc[i][j][e];
        }
    }
  }
}

__global__ void cvt_f32_bf16(const float* __restrict__ in,
                             bf16* __restrict__ out, long n4) {
  long i = blockIdx.x * (long)blockDim.x + threadIdx.x;
  const long stride = (long)gridDim.x * blockDim.x;
  for (; i < n4; i += stride) {
    const float4 f = ((const float4*)in)[i];
    union { ushort4 u; bf16 h[4]; } p;
    p.h[0] = (bf16)f.x;
    p.h[1] = (bf16)f.y;
    p.h[2] = (bf16)f.z;
    p.h[3] = (bf16)f.w;
    ((ushort4*)out)[i] = p.u;
  }
}

// vt[b][d][m] = v[b][m][d] / Z[b][m]; v lives in kv (cols 512..1535, ld 1536)
__global__ __launch_bounds__(256) void transpose_scale(
    const bf16* __restrict__ kv, const float* __restrict__ Z,
    bf16* __restrict__ vt) {
  __shared__ bf16 tile[32][33];
  const int b = blockIdx.z;
  const bf16* vb = kv + (long)b * 2048 * 1536 + 512;
  bf16* vtb = vt + (long)b * 1024 * 2048;
  const float* Zb = Z + b * 2048;
  const int m0 = blockIdx.x * 32, d0 = blockIdx.y * 32;
  const int t = threadIdx.x;
  const int r = t >> 3, c4 = (t & 7) * 4;

  union { ushort4 u; bf16 h[4]; } in;
  in.u = *(const ushort4*)&vb[(long)(m0 + r) * 1536 + d0 + c4];
  tile[r][c4 + 0] = in.h[0];
  tile[r][c4 + 1] = in.h[1];
  tile[r][c4 + 2] = in.h[2];
  tile[r][c4 + 3] = in.h[3];
  __syncthreads();

  union { ushort4 u; bf16 h[4]; } o;
#pragma unroll
  for (int j = 0; j < 4; j++)
    o.h[j] = (bf16)((float)tile[c4 + j][r] / Zb[m0 + c4 + j]);
  *(ushort4*)&vtb[(long)(d0 + r) * 2048 + m0 + c4] = o.u;
}

extern "C" void kernel_launch(void* const* d_in, const int* in_sizes, int n_in,
                              void* d_out, int out_size, void* d_ws,
                              size_t ws_size, hipStream_t stream) {
  const float* y = (const float*)d_in[0];   // [8,2048,1024]
  const float* x = (const float*)d_in[1];   // [8,2048,1024]
  const float* Wq = (const float*)d_in[2];  // [512,1024]
  const float* bq = (const float*)d_in[3];
  const float* Wk = (const float*)d_in[4];  // [512,1024]
  const float* bk = (const float*)d_in[5];
  const float* Wv = (const float*)d_in[6];  // [1024,1024]
  const float* bv = (const float*)d_in[7];
  float* out = (float*)d_out;

  constexpr long B = 8, Nq = 2048, Nk = 2048, Cd = 1024, CH = 512;
  constexpr long BN = B * Nq;  // 16384
  const float scale = 0.04419417382415922f;  // 512^-0.5

  char* w = (char*)d_ws;
  auto alloc = [&](size_t bytes) {
    char* p = w;
    w += (bytes + 255) & ~(size_t)255;
    return p;
  };
  bf16* y_bf = (bf16*)alloc(BN * Cd * 2);          // 33.5 MB
  bf16* x_bf = (bf16*)alloc(BN * Cd * 2);          // 33.5 MB
  bf16* Wq_bf = (bf16*)alloc(CH * Cd * 2);         // 1 MB
  bf16* Wkv_bf = (bf16*)alloc((CH + Cd) * Cd * 2); // 3 MB (Wk | Wv rows)
  float* bkv = (float*)alloc((CH + Cd) * 4);
  bf16* q_bf = (bf16*)alloc(BN * CH * 2);          // 16.8 MB
  bf16* kv_bf = (bf16*)alloc(BN * (CH + Cd) * 2);  // 50.3 MB
  bf16* vt_bf = (bf16*)alloc(BN * Cd * 2);         // 33.5 MB
  bf16* P_bf = (bf16*)alloc(B * Nq * Nk * 2);      // 67 MB
  float* Zsum = (float*)alloc(B * Nk * 4);
  if ((size_t)(w - (char*)d_ws) > ws_size) return;

  // ---- fp32 -> bf16 (Wk,Wv concatenated into Wkv)
  cvt_f32_bf16<<<2048, 256, 0, stream>>>(y, y_bf, BN * Cd / 4);
  cvt_f32_bf16<<<2048, 256, 0, stream>>>(x, x_bf, BN * Cd / 4);
  cvt_f32_bf16<<<512, 256, 0, stream>>>(Wq, Wq_bf, CH * Cd / 4);
  cvt_f32_bf16<<<512, 256, 0, stream>>>(Wk, Wkv_bf, CH * Cd / 4);
  cvt_f32_bf16<<<1024, 256, 0, stream>>>(Wv, Wkv_bf + CH * Cd, Cd * Cd / 4);
  hipMemcpyAsync(bkv, bk, CH * 4, hipMemcpyDeviceToDevice, stream);
  hipMemcpyAsync(bkv + CH, bv, Cd * 4, hipMemcpyDeviceToDevice, stream);

  // ---- q = y Wq^T + bq ; kv = x Wkv^T + bkv
  gemm128<EPI_BIAS><<<dim3(128, 4, 1), 256, 0, stream>>>(
      y_bf, Wq_bf, q_bf, bq, nullptr, BN, CH, Cd, Cd, Cd, CH, 0, 0, 0, 0.f);
  gemm128<EPI_BIAS><<<dim3(128, 12, 1), 256, 0, stream>>>(
      x_bf, Wkv_bf, kv_bf, bkv, nullptr, BN, CH + Cd, Cd, Cd, Cd, CH + Cd,
      0, 0, 0, 0.f);

  // ---- P = exp(q k^T * scale), Z[m] = colsum over n
  hipMemsetAsync(Zsum, 0, B * Nk * 4, stream);
  gemm128<EPI_EXP><<<dim3(16, 16, 8), 256, 0, stream>>>(
      q_bf, kv_bf, P_bf, nullptr, Zsum, Nq, Nk, CH, CH, CH + Cd, Nk,
      Nq * CH, Nk * (CH + Cd), Nq * Nk, scale);

  // ---- vt[d,m] = v[m,d] / Z[m]
  transpose_scale<<<dim3(64, 32, 8), 256, 0, stream>>>(kv_bf, Zsum, vt_bf);

  // ---- out = P vt^T (fp32)
  gemm128<EPI_OUT><<<dim3(16, 8, 8), 256, 0, stream>>>(
      P_bf, vt_bf, out, nullptr, nullptr, Nq, Cd, Nk, Nk, Nk, Cd,
      Nq * Nk, Cd * Nk, Nq * Cd, 0.f);
}